// Round 10
// baseline (92.835 us; speedup 1.0000x reference)
//
#include <hip/hip_runtime.h>
#include <stdint.h>

typedef unsigned short u16;
typedef __attribute__((ext_vector_type(4))) float f32x4;
typedef __attribute__((ext_vector_type(8))) __bf16 bf16x8;

// ---- Cayley table for Cl(3,0), basis order [1,e1,e2,e3,e12,e13,e23,e123] ----
struct Cay { int idx[8][8]; float sgn[8][8]; };
constexpr int kOrder[8] = {0,1,2,4,3,5,6,7};
constexpr int ordpos(int m){ int r=-1; for(int i=0;i<8;i++) if(kOrder[i]==m) r=i; return r; }
constexpr Cay make_cay(){
  Cay c{};
  for(int ia=0; ia<8; ia++) for(int ib=0; ib<8; ib++){
    int a=kOrder[ia], b=kOrder[ib];
    int t=a>>1, tot=0;
    while(t){ int x=t&b; while(x){ tot+=x&1; x>>=1; } t>>=1; }
    c.idx[ia][ib]=ordpos(a^b);
    c.sgn[ia][ib]=(tot&1)?-1.0f:1.0f;
  }
  return c;
}
constexpr Cay CAY = make_cay();

// ---- squared-multivector GP at HALF SCALE for k!=0 (x2 folded into W2 grades 1..3) ----
struct GPTab { float dsgn[8]; int np; int pi[28]; int pj[28]; int pk[28]; float ps[28]; };
constexpr GPTab make_gptab(){
  GPTab t{};
  for (int i=0;i<8;i++) t.dsgn[i] = CAY.sgn[i][i];
  t.np = 0;
  for (int i=0;i<8;i++) for (int j=i+1;j<8;j++){
    float s = CAY.sgn[i][j] + CAY.sgn[j][i];      // in {-2,0,+2}
    if (s != 0.0f){ t.pi[t.np]=i; t.pj[t.np]=j; t.pk[t.np]=CAY.idx[i][j];
                    t.ps[t.np]=(s>0.f)?1.0f:-1.0f; t.np++; }
  }
  return t;
}
constexpr GPTab GPT = make_gptab();

__device__ __forceinline__ void gprod_half(const float* h, float* g){
  float g0 = h[0]*h[0];
  #pragma unroll
  for (int i=1;i<8;i++) g0 = fmaf(GPT.dsgn[i]>0.f ? h[i] : -h[i], h[i], g0);
  g[0] = g0;
  #pragma unroll
  for (int k=1;k<8;k++) g[k] = 0.f;
  #pragma unroll
  for (int t=0;t<GPT.np;t++)
    g[GPT.pk[t]] = fmaf(GPT.ps[t]>0.f ? h[GPT.pi[t]] : -h[GPT.pi[t]],
                        h[GPT.pj[t]], g[GPT.pk[t]]);
}

__device__ __forceinline__ u16 f2bf(float f){
  union { float f; uint32_t u; } v; v.f=f;
  uint32_t u=v.u;
  return (u16)((u + 0x7fffu + ((u>>16)&1u)) >> 16);   // RNE
}

__device__ __forceinline__ uint32_t cvtpk(float lo, float hi){
  uint32_t r;
  asm("v_cvt_pk_bf16_f32 %0, %1, %2" : "=v"(r) : "v"(lo), "v"(hi));
  return r;
}

// ---- weight repack ----
// w1p frag f=((g*2+ks)*8+ot): lane l, elem e -> W1[ot*16+(l&15)][ks*32+(l>>4)*8+e][g]
// w2p frag f=((g*4+ks)*4+ot): lane l, elem e -> W2[ot*16+(l&15)][ks*32+(l>>4)*8+e][g] * (g?2:1)
__global__ void gp_prepack(const float* __restrict__ W1, const float* __restrict__ W2,
                           u16* __restrict__ w1p, u16* __restrict__ w2p)
{
  int t = blockIdx.x*256 + threadIdx.x;   // 0..65535
  int e = t & 7, l = (t>>3)&63, f = t>>9;
  int lm = l & 15, lh = l >> 4;
  if (f < 64) {
    int g = f >> 4, ks = (f>>3)&1, ot = f&7;
    int o = ot*16 + lm, c = ks*32 + lh*8 + e;
    w1p[f*512 + l*8 + e] = f2bf(W1[(o*64 + c)*4 + g]);
  } else {
    int f2 = f - 64;
    int g = f2 >> 4, ks = (f2>>2)&3, ot = f2&3;
    int outc = ot*16 + lm, o = ks*32 + lh*8 + e;
    float sc = (g == 0) ? 1.0f : 2.0f;               // half-scale GP compensation
    w2p[f2*512 + l*8 + e] = f2bf(W2[(outc*128 + o)*4 + g] * sc);
  }
}

// ---- per-tile macros (R4 body; static register naming) ----
#define GP_LOADRX(RX, TILE) do {                                             \
    const float4* _s0 = xb + (size_t)(TILE) * 2048;                          \
    _Pragma("unroll")                                                        \
    for (int _it=0; _it<2; ++_it){                                           \
      const float4* _s = _s0 + (pr + _it*8)*128 + cp*4;                      \
      RX[_it*4+0]=_s[0]; RX[_it*4+1]=_s[1];                                  \
      RX[_it*4+2]=_s[2]; RX[_it*4+3]=_s[3];                                  \
    } } while(0)

#define GP_STAGE(RX) do {                                                    \
    _Pragma("unroll")                                                        \
    for (int _it=0; _it<2; ++_it){                                           \
      const int _p = pr + _it*8;                                             \
      float4 _v0=RX[_it*4+0], _v1=RX[_it*4+1], _v2=RX[_it*4+2], _v3=RX[_it*4+3]; \
      uint32_t _pk[8];                                                       \
      _pk[0]=cvtpk(_v0.x,_v2.x); _pk[1]=cvtpk(_v0.y,_v2.y);                  \
      _pk[2]=cvtpk(_v0.z,_v2.z); _pk[3]=cvtpk(_v0.w,_v2.w);                  \
      _pk[4]=cvtpk(_v1.x,_v3.x); _pk[5]=cvtpk(_v1.y,_v3.y);                  \
      _pk[6]=cvtpk(_v1.z,_v3.z); _pk[7]=cvtpk(_v1.w,_v3.w);                  \
      const int _xo = (_p & 7) << 4;                                         \
      _Pragma("unroll")                                                      \
      for (int _b=0;_b<8;_b++)                                               \
        *reinterpret_cast<uint32_t*>(SH + ((((_p*8+_b)<<7) + (cp<<2)) ^ _xo)) = _pk[_b]; \
    } } while(0)

#define GP_BODY(T, CUR, NXT, DOPF) do {                                      \
    const size_t tile = (size_t)blockIdx.x*2 + (T);                          \
    GP_STAGE(CUR);                                                           \
    __syncthreads();                                  /* b1: X ready */      \
    /* ---- stage 1: H = W1 * X ---- */                                      \
    f32x4 acc1[2][8];                                                        \
    _Pragma("unroll")                                                        \
    for (int cc=0; cc<2; ++cc)                                               \
      _Pragma("unroll")                                                      \
      for (int b=0; b<8; ++b) acc1[cc][b] = (f32x4){0.f,0.f,0.f,0.f};        \
    _Pragma("unroll")                                                        \
    for (int g4=0; g4<4; ++g4){                                              \
      _Pragma("unroll")                                                      \
      for (int ks=0; ks<2; ++ks){                                            \
        uint4 wa = w1f[((g4*2+ks)*8 + w    )*64 + l];                        \
        uint4 wb = w1f[((g4*2+ks)*8 + w + 4)*64 + l];                        \
        bf16x8 wav = __builtin_bit_cast(bf16x8, wa);                         \
        bf16x8 wbv = __builtin_bit_cast(bf16x8, wb);                         \
        _Pragma("unroll")                                                    \
        for (int bi=0; bi<3; ++bi){                                          \
          if (bi >= BCNT[g4]) break;                                         \
          const int blade = BSTART[g4] + bi;                                 \
          bf16x8 xv = *reinterpret_cast<const bf16x8*>(                      \
              SH + ((((lm*8+blade)<<7) + ((ks*32+lh*8)<<1)) ^ xk));          \
          acc1[0][blade] = __builtin_amdgcn_mfma_f32_16x16x32_bf16(wav, xv, acc1[0][blade], 0,0,0); \
          acc1[1][blade] = __builtin_amdgcn_mfma_f32_16x16x32_bf16(wbv, xv, acc1[1][blade], 0,0,0); \
        }                                                                    \
      }                                                                      \
    }                                                                        \
    __syncthreads();                                  /* b2: X reads done */ \
    /* ---- GP (half-scale) + packed G writes ---- */                        \
    _Pragma("unroll")                                                        \
    for (int cc=0; cc<2; ++cc){                                              \
      const int cht = w + cc*4;                                              \
      const float4 b14 = b1f[cht*4 + lh];                                    \
      const float bb[4] = {b14.x, b14.y, b14.z, b14.w};                      \
      uint32_t glo[8], ghi[8];                                               \
      _Pragma("unroll")                                                      \
      for (int rp=0; rp<2; ++rp){                                            \
        float ga[8], gb[8];                                                  \
        {                                                                    \
          float h[8];                                                        \
          _Pragma("unroll")                                                  \
          for (int b=0;b<8;b++) h[b] = acc1[cc][b][rp*2+0];                  \
          h[0] += bb[rp*2+0];                                                \
          gprod_half(h, ga);                                                 \
        }                                                                    \
        {                                                                    \
          float h[8];                                                        \
          _Pragma("unroll")                                                  \
          for (int b=0;b<8;b++) h[b] = acc1[cc][b][rp*2+1];                  \
          h[0] += bb[rp*2+1];                                                \
          gprod_half(h, gb);                                                 \
        }                                                                    \
        _Pragma("unroll")                                                    \
        for (int b=0;b<8;b++){                                               \
          uint32_t v = cvtpk(ga[b], gb[b]);                                  \
          if (rp==0) glo[b] = v; else ghi[b] = v;                            \
        }                                                                    \
      }                                                                      \
      const int chByte = (cht*16 + lh*4) << 1;                               \
      _Pragma("unroll")                                                      \
      for (int b=0;b<8;b++){                                                 \
        uint2 v; v.x = glo[b]; v.y = ghi[b];                                 \
        *reinterpret_cast<uint2*>(SH + ((((lm*8+b)<<8) + chByte) ^ xk)) = v; \
      }                                                                      \
    }                                                                        \
    /* ---- T14: issue next tile's x loads; hide under stage2+epi ---- */    \
    if (DOPF){ GP_LOADRX(NXT, tile+1); asm volatile("" ::: "memory"); }      \
    __syncthreads();                                  /* b3: G ready */      \
    /* ---- stage 2: Y = G * W2 ---- */                                      \
    f32x4 acc2[8];                                                           \
    _Pragma("unroll")                                                        \
    for (int b=0; b<8; ++b) acc2[b] = (f32x4){0.f,0.f,0.f,0.f};              \
    _Pragma("unroll")                                                        \
    for (int ks=0; ks<4; ++ks){                                              \
      _Pragma("unroll")                                                      \
      for (int g4=0; g4<4; ++g4){                                            \
        uint4 wu = w2f[((g4*4+ks)*4 + w)*64 + l];                            \
        bf16x8 wv = __builtin_bit_cast(bf16x8, wu);                          \
        _Pragma("unroll")                                                    \
        for (int bi=0; bi<3; ++bi){                                          \
          if (bi >= BCNT[g4]) break;                                         \
          const int blade = BSTART[g4] + bi;                                 \
          bf16x8 gv = *reinterpret_cast<const bf16x8*>(                      \
              SH + ((((lm*8+blade)<<8) + ((ks*32+lh*8)<<1)) ^ xk));          \
          acc2[blade] = __builtin_amdgcn_mfma_f32_16x16x32_bf16(gv, wv, acc2[blade], 0,0,0); \
        }                                                                    \
      }                                                                      \
    }                                                                        \
    /* ---- epilogue ---- */                                                 \
    _Pragma("unroll")                                                        \
    for (int r=0; r<4; ++r) acc2[0][r] += b2v;                               \
    float nrm[4];                                                            \
    _Pragma("unroll")                                                        \
    for (int r=0; r<4; ++r){                                                 \
      float s = 0.f;                                                         \
      _Pragma("unroll")                                                      \
      for (int b=0; b<8; ++b) s = fmaf(acc2[b][r], acc2[b][r], s);           \
      nrm[r] = sqrtf(s);                                                     \
    }                                                                        \
    _Pragma("unroll")                                                        \
    for (int r=0; r<4; ++r){                                                 \
      float v = nrm[r];                                                      \
      v += __shfl_xor(v, 1, 64);                                             \
      v += __shfl_xor(v, 2, 64);                                             \
      v += __shfl_xor(v, 4, 64);                                             \
      v += __shfl_xor(v, 8, 64);                                             \
      nrm[r] = v;                                                            \
    }                                                                        \
    if (lm == 0){                                                            \
      _Pragma("unroll")                                                      \
      for (int r=0; r<4; ++r) redArr[(lh*4 + r)*4 + w] = nrm[r];             \
    }                                                                        \
    __syncthreads();                                  /* b4: norms ready */  \
    _Pragma("unroll")                                                        \
    for (int r=0; r<4; ++r){                                                 \
      const int pos = lh*4 + r;                                              \
      const float4 rr = *reinterpret_cast<const float4*>(redArr + pos*4);    \
      const float denom = (rr.x+rr.y+rr.z+rr.w) * (1.0f/64.0f) + 1e-6f;      \
      const float sc = aval * __builtin_amdgcn_rcpf(denom);                  \
      float4 o0, o1;                                                         \
      o0.x = acc2[0][r]*sc; o0.y = acc2[1][r]*sc;                            \
      o0.z = acc2[2][r]*sc; o0.w = acc2[3][r]*sc;                            \
      o1.x = acc2[4][r]*sc; o1.y = acc2[5][r]*sc;                            \
      o1.z = acc2[6][r]*sc; o1.w = acc2[7][r]*sc;                            \
      size_t P = tile*16 + pos;                                              \
      float4* op = reinterpret_cast<float4*>(out + (P*64 + (size_t)oc)*8);   \
      op[0] = o0; op[1] = o1;                                                \
    }                                                                        \
  } while(0)

// LDS: X 16KB aliases low half of G 32KB (both swizzled byte ^= ((pos&7)<<4));
// redArr lives OUTSIDE the alias region at SH+32768 -> no redArr barrier needed.
// grid 1024 = 4 blocks/CU resident, single generation, 2 tiles/block pipelined.
__global__ __launch_bounds__(256,4) void gp_fused(
    const float* __restrict__ x, const u16* __restrict__ w1p,
    const float* __restrict__ b1, const u16* __restrict__ w2p,
    const float* __restrict__ b2, const float* __restrict__ avec,
    float* __restrict__ out)
{
  __shared__ __align__(16) char SH[33024];
  float* redArr = reinterpret_cast<float*>(SH + 32768);   // [pos][w], 16x4 floats

  const int tid = threadIdx.x;
  const int w  = tid >> 6;     // wave 0..3
  const int l  = tid & 63;
  const int lm = l & 15;
  const int lh = l >> 4;
  const int xk = (lm & 7) << 4;
  const int cp = tid & 31;
  const int pr = tid >> 5;

  constexpr int BSTART[4] = {0,1,4,7};
  constexpr int BCNT[4]   = {1,3,3,1};

  const float4* xb  = reinterpret_cast<const float4*>(x);
  const uint4*  w1f = reinterpret_cast<const uint4*>(w1p);
  const uint4*  w2f = reinterpret_cast<const uint4*>(w2p);
  const float4* b1f = reinterpret_cast<const float4*>(b1);

  const int oc = w*16 + lm;
  const float b2v  = b2[oc];
  const float aval = avec[oc];

  float4 rxA[8], rxB[8];
  GP_LOADRX(rxA, (size_t)blockIdx.x*2);
  asm volatile("" ::: "memory");     // pin tile-0 loads before staging

  GP_BODY(0, rxA, rxB, 1);
  GP_BODY(1, rxB, rxA, 0);
}

extern "C" void kernel_launch(void* const* d_in, const int* in_sizes, int n_in,
                              void* d_out, int out_size, void* d_ws, size_t ws_size,
                              hipStream_t stream)
{
  const float* x  = (const float*)d_in[0];
  const float* W1 = (const float*)d_in[1];
  const float* b1 = (const float*)d_in[2];
  const float* W2 = (const float*)d_in[3];
  const float* b2 = (const float*)d_in[4];
  const float* a  = (const float*)d_in[5];
  float* out = (float*)d_out;

  u16* w1p = (u16*)d_ws;          // 64 KB
  u16* w2p = w1p + 32768;         // 64 KB

  gp_prepack<<<256, 256, 0, stream>>>(W1, W2, w1p, w2p);
  gp_fused<<<1024, 256, 0, stream>>>(x, w1p, b1, w2p, b2, a, out);
}

// Round 11
// 44.960 us; speedup vs baseline: 2.0648x; 2.0648x over previous
//
#include <hip/hip_runtime.h>
#include <stdint.h>

typedef unsigned short u16;
typedef __attribute__((ext_vector_type(4))) float f32x4;
typedef __attribute__((ext_vector_type(8))) __bf16 bf16x8;

// ---- Cayley table for Cl(3,0), basis order [1,e1,e2,e3,e12,e13,e23,e123] ----
struct Cay { int idx[8][8]; float sgn[8][8]; };
constexpr int kOrder[8] = {0,1,2,4,3,5,6,7};
constexpr int ordpos(int m){ int r=-1; for(int i=0;i<8;i++) if(kOrder[i]==m) r=i; return r; }
constexpr Cay make_cay(){
  Cay c{};
  for(int ia=0; ia<8; ia++) for(int ib=0; ib<8; ib++){
    int a=kOrder[ia], b=kOrder[ib];
    int t=a>>1, tot=0;
    while(t){ int x=t&b; while(x){ tot+=x&1; x>>=1; } t>>=1; }
    c.idx[ia][ib]=ordpos(a^b);
    c.sgn[ia][ib]=(tot&1)?-1.0f:1.0f;
  }
  return c;
}
constexpr Cay CAY = make_cay();

// ---- squared-multivector GP at HALF SCALE for k!=0 (x2 folded into W2 grades 1..3) ----
struct GPTab { float dsgn[8]; int np; int pi[28]; int pj[28]; int pk[28]; float ps[28]; };
constexpr GPTab make_gptab(){
  GPTab t{};
  for (int i=0;i<8;i++) t.dsgn[i] = CAY.sgn[i][i];
  t.np = 0;
  for (int i=0;i<8;i++) for (int j=i+1;j<8;j++){
    float s = CAY.sgn[i][j] + CAY.sgn[j][i];      // in {-2,0,+2}
    if (s != 0.0f){ t.pi[t.np]=i; t.pj[t.np]=j; t.pk[t.np]=CAY.idx[i][j];
                    t.ps[t.np]=(s>0.f)?1.0f:-1.0f; t.np++; }
  }
  return t;
}
constexpr GPTab GPT = make_gptab();

__device__ __forceinline__ void gprod_half(const float* h, float* g){
  float g0 = h[0]*h[0];
  #pragma unroll
  for (int i=1;i<8;i++) g0 = fmaf(GPT.dsgn[i]>0.f ? h[i] : -h[i], h[i], g0);
  g[0] = g0;
  #pragma unroll
  for (int k=1;k<8;k++) g[k] = 0.f;
  #pragma unroll
  for (int t=0;t<GPT.np;t++)
    g[GPT.pk[t]] = fmaf(GPT.ps[t]>0.f ? h[GPT.pi[t]] : -h[GPT.pi[t]],
                        h[GPT.pj[t]], g[GPT.pk[t]]);
}

__device__ __forceinline__ u16 f2bf(float f){
  union { float f; uint32_t u; } v; v.f=f;
  uint32_t u=v.u;
  return (u16)((u + 0x7fffu + ((u>>16)&1u)) >> 16);   // RNE
}

__device__ __forceinline__ uint32_t cvtpk(float lo, float hi){
  uint32_t r;
  asm("v_cvt_pk_bf16_f32 %0, %1, %2" : "=v"(r) : "v"(lo), "v"(hi));
  return r;
}

// ---- weight repack ----
// w1p frag f=((g*2+ks)*8+ot): lane l, elem e -> W1[ot*16+(l&15)][ks*32+(l>>4)*8+e][g]
// w2p frag f=((g*4+ks)*4+ot): lane l, elem e -> W2[ot*16+(l&15)][ks*32+(l>>4)*8+e][g] * (g?2:1)
__global__ void gp_prepack(const float* __restrict__ W1, const float* __restrict__ W2,
                           u16* __restrict__ w1p, u16* __restrict__ w2p)
{
  int t = blockIdx.x*256 + threadIdx.x;   // 0..65535
  int e = t & 7, l = (t>>3)&63, f = t>>9;
  int lm = l & 15, lh = l >> 4;
  if (f < 64) {
    int g = f >> 4, ks = (f>>3)&1, ot = f&7;
    int o = ot*16 + lm, c = ks*32 + lh*8 + e;
    w1p[f*512 + l*8 + e] = f2bf(W1[(o*64 + c)*4 + g]);
  } else {
    int f2 = f - 64;
    int g = f2 >> 4, ks = (f2>>2)&3, ot = f2&3;
    int outc = ot*16 + lm, o = ks*32 + lh*8 + e;
    float sc = (g == 0) ? 1.0f : 2.0f;               // half-scale GP compensation
    w2p[f2*512 + l*8 + e] = f2bf(W2[(outc*128 + o)*4 + g] * sc);
  }
}

// LDS map (33 KB, 4 blocks/CU):
//   [0,16K)   X tile [pos16][blade8][ch-in 64] bf16, 128 B rows — later G1 (ch 64..127)
//   [16K,32K) G0 tile [pos16][blade8][ch 0..63] bf16, 128 B rows
//   [32K,+256) redArr (disjoint -> no alias barrier)
// All rows swizzled within-row: inner_byte ^= ((pos&7)<<4).
// Schedule: stage X | b1 | s1cc0+GP->G0 | b2 | {s1cc1+GP->regs ; s2 ks01(G0)} | b3 |
//           write G1 | b4 | s2 ks23(G1) + norms | b5 | scale+store.
// acc1 is 32 regs (cc-sequential) -> peak regs ~105 -> 4 waves/SIMD.
__global__ __launch_bounds__(256,4) void gp_fused(
    const float* __restrict__ x, const u16* __restrict__ w1p,
    const float* __restrict__ b1, const u16* __restrict__ w2p,
    const float* __restrict__ b2, const float* __restrict__ avec,
    float* __restrict__ out)
{
  __shared__ __align__(16) char SH[33024];
  float* redArr = reinterpret_cast<float*>(SH + 32768);   // [pos][w], 16x4 floats
  char* G0 = SH + 16384;

  const int tid = threadIdx.x;
  const int w  = tid >> 6;     // wave 0..3
  const int l  = tid & 63;
  const int lm = l & 15;
  const int lh = l >> 4;
  const int xk = (lm & 7) << 4;   // within-row swizzle key (pos = lm on read side)

  constexpr int BSTART[4] = {0,1,4,7};
  constexpr int BCNT[4]   = {1,3,3,1};

  const float4* xb  = reinterpret_cast<const float4*>(x);
  const uint4*  w1f = reinterpret_cast<const uint4*>(w1p);
  const uint4*  w2f = reinterpret_cast<const uint4*>(w2p);
  const float4* b1f = reinterpret_cast<const float4*>(b1);

  const int oc = w*16 + lm;
  const float b2v  = b2[oc];
  const float aval = avec[oc];

  // ---- stage X: 16 pos x 64 cin x 8 blades -> LDS @0, packed bf16 writes ----
  {
    const int cp = tid & 31;          // c-pair: c0 = 2*cp
    const int pr = tid >> 5;          // 0..7
    const float4* xt = xb + (size_t)blockIdx.x * 2048;
    #pragma unroll
    for (int it=0; it<2; ++it){
      const int p = pr + it*8;
      const float4* src = xt + p*128 + cp*4;
      float4 v0 = src[0], v1 = src[1], v2 = src[2], v3 = src[3];
      uint32_t pk[8];
      pk[0]=cvtpk(v0.x,v2.x); pk[1]=cvtpk(v0.y,v2.y); pk[2]=cvtpk(v0.z,v2.z); pk[3]=cvtpk(v0.w,v2.w);
      pk[4]=cvtpk(v1.x,v3.x); pk[5]=cvtpk(v1.y,v3.y); pk[6]=cvtpk(v1.z,v3.z); pk[7]=cvtpk(v1.w,v3.w);
      const int xo = (p & 7) << 4;
      #pragma unroll
      for (int b=0;b<8;b++)
        *reinterpret_cast<uint32_t*>(SH + (((p*8+b)<<7) + ((cp<<2) ^ xo))) = pk[b];
    }
  }
  __syncthreads();                                   // bar1: X ready

  // ================= phase A: s1 cc0 + GP -> G0 (X untouched) =================
  {
    f32x4 acc1[8];
    #pragma unroll
    for (int b=0;b<8;++b) acc1[b] = (f32x4){0.f,0.f,0.f,0.f};
    #pragma unroll
    for (int g4=0; g4<4; ++g4){
      #pragma unroll
      for (int ks=0; ks<2; ++ks){
        uint4 wu = w1f[((g4*2+ks)*8 + w)*64 + l];
        bf16x8 wv = __builtin_bit_cast(bf16x8, wu);
        #pragma unroll
        for (int bi=0; bi<3; ++bi){
          if (bi >= BCNT[g4]) break;
          const int blade = BSTART[g4] + bi;
          bf16x8 xv = *reinterpret_cast<const bf16x8*>(
              SH + (((lm*8+blade)<<7) + (((ks*32+lh*8)<<1) ^ xk)));
          acc1[blade] = __builtin_amdgcn_mfma_f32_16x16x32_bf16(wv, xv, acc1[blade], 0,0,0);
        }
      }
    }
    // GP cc0 (cht = w), write G0
    const float4 b14 = b1f[w*4 + lh];
    const float bb[4] = {b14.x, b14.y, b14.z, b14.w};
    uint32_t glo[8], ghi[8];
    #pragma unroll
    for (int rp=0; rp<2; ++rp){
      float ga[8], gb[8];
      { float h[8];
        #pragma unroll
        for (int b=0;b<8;b++) h[b] = acc1[b][rp*2+0];
        h[0] += bb[rp*2+0]; gprod_half(h, ga); }
      { float h[8];
        #pragma unroll
        for (int b=0;b<8;b++) h[b] = acc1[b][rp*2+1];
        h[0] += bb[rp*2+1]; gprod_half(h, gb); }
      #pragma unroll
      for (int b=0;b<8;b++){
        uint32_t v = cvtpk(ga[b], gb[b]);
        if (rp==0) glo[b] = v; else ghi[b] = v;
      }
    }
    const int chB = w*32 + lh*8;          // within-row byte, ch 0..63 half
    #pragma unroll
    for (int b=0;b<8;b++){
      uint2 v; v.x = glo[b]; v.y = ghi[b];
      *reinterpret_cast<uint2*>(G0 + (((lm*8+b)<<7) + (chB ^ xk))) = v;
    }
  }
  __syncthreads();                                   // bar2: G0 ready

  // ============ phase B: s1 cc1 + GP (held in regs)  ∥  s2 ks=0,1 (G0) ============
  uint32_t g1lo[8], g1hi[8];
  {
    f32x4 acc1[8];
    #pragma unroll
    for (int b=0;b<8;++b) acc1[b] = (f32x4){0.f,0.f,0.f,0.f};
    #pragma unroll
    for (int g4=0; g4<4; ++g4){
      #pragma unroll
      for (int ks=0; ks<2; ++ks){
        uint4 wu = w1f[((g4*2+ks)*8 + w + 4)*64 + l];
        bf16x8 wv = __builtin_bit_cast(bf16x8, wu);
        #pragma unroll
        for (int bi=0; bi<3; ++bi){
          if (bi >= BCNT[g4]) break;
          const int blade = BSTART[g4] + bi;
          bf16x8 xv = *reinterpret_cast<const bf16x8*>(
              SH + (((lm*8+blade)<<7) + (((ks*32+lh*8)<<1) ^ xk)));
          acc1[blade] = __builtin_amdgcn_mfma_f32_16x16x32_bf16(wv, xv, acc1[blade], 0,0,0);
        }
      }
    }
    const float4 b14 = b1f[(w+4)*4 + lh];
    const float bb[4] = {b14.x, b14.y, b14.z, b14.w};
    #pragma unroll
    for (int rp=0; rp<2; ++rp){
      float ga[8], gb[8];
      { float h[8];
        #pragma unroll
        for (int b=0;b<8;b++) h[b] = acc1[b][rp*2+0];
        h[0] += bb[rp*2+0]; gprod_half(h, ga); }
      { float h[8];
        #pragma unroll
        for (int b=0;b<8;b++) h[b] = acc1[b][rp*2+1];
        h[0] += bb[rp*2+1]; gprod_half(h, gb); }
      #pragma unroll
      for (int b=0;b<8;b++){
        uint32_t v = cvtpk(ga[b], gb[b]);
        if (rp==0) g1lo[b] = v; else g1hi[b] = v;
      }
    }
  }

  f32x4 acc2[8];
  #pragma unroll
  for (int b=0;b<8;++b) acc2[b] = (f32x4){0.f,0.f,0.f,0.f};
  #pragma unroll
  for (int ks=0; ks<2; ++ks){
    #pragma unroll
    for (int g4=0; g4<4; ++g4){
      uint4 wu = w2f[((g4*4+ks)*4 + w)*64 + l];
      bf16x8 wv = __builtin_bit_cast(bf16x8, wu);
      #pragma unroll
      for (int bi=0; bi<3; ++bi){
        if (bi >= BCNT[g4]) break;
        const int blade = BSTART[g4] + bi;
        bf16x8 gv = *reinterpret_cast<const bf16x8*>(
            G0 + (((lm*8+blade)<<7) + ((ks*64 + lh*16) ^ xk)));
        acc2[blade] = __builtin_amdgcn_mfma_f32_16x16x32_bf16(gv, wv, acc2[blade], 0,0,0);
      }
    }
  }
  __syncthreads();                                   // bar3: X dead everywhere

  // ---- write G1 (ch 64..127) into the old X region @0 ----
  {
    const int chB = w*32 + lh*8;
    #pragma unroll
    for (int b=0;b<8;b++){
      uint2 v; v.x = g1lo[b]; v.y = g1hi[b];
      *reinterpret_cast<uint2*>(SH + (((lm*8+b)<<7) + (chB ^ xk))) = v;
    }
  }
  __syncthreads();                                   // bar4: G1 ready

  // ---- s2 ks=2,3 (G1) ----
  #pragma unroll
  for (int ks=2; ks<4; ++ks){
    #pragma unroll
    for (int g4=0; g4<4; ++g4){
      uint4 wu = w2f[((g4*4+ks)*4 + w)*64 + l];
      bf16x8 wv = __builtin_bit_cast(bf16x8, wu);
      #pragma unroll
      for (int bi=0; bi<3; ++bi){
        if (bi >= BCNT[g4]) break;
        const int blade = BSTART[g4] + bi;
        bf16x8 gv = *reinterpret_cast<const bf16x8*>(
            SH + (((lm*8+blade)<<7) + (((ks-2)*64 + lh*16) ^ xk)));
        acc2[blade] = __builtin_amdgcn_mfma_f32_16x16x32_bf16(gv, wv, acc2[blade], 0,0,0);
      }
    }
  }

  // ---- epilogue: bias, norms, per-position mean over 64 channels, scale, store ----
  #pragma unroll
  for (int r=0; r<4; ++r) acc2[0][r] += b2v;

  float nrm[4];
  #pragma unroll
  for (int r=0; r<4; ++r) {
    float s = 0.f;
    #pragma unroll
    for (int b=0; b<8; ++b) s = fmaf(acc2[b][r], acc2[b][r], s);
    nrm[r] = sqrtf(s);
  }
  #pragma unroll
  for (int r=0; r<4; ++r) {
    float v = nrm[r];
    v += __shfl_xor(v, 1, 64);
    v += __shfl_xor(v, 2, 64);
    v += __shfl_xor(v, 4, 64);
    v += __shfl_xor(v, 8, 64);
    nrm[r] = v;                         // sum over this wave's 16 channels
  }
  if (lm == 0) {
    #pragma unroll
    for (int r=0; r<4; ++r) redArr[(lh*4 + r)*4 + w] = nrm[r];
  }
  __syncthreads();                                   // bar5: norms ready

  #pragma unroll
  for (int r=0; r<4; ++r) {
    const int pos = lh*4 + r;
    const float4 rr = *reinterpret_cast<const float4*>(redArr + pos*4);
    const float denom = (rr.x+rr.y+rr.z+rr.w) * (1.0f/64.0f) + 1e-6f;
    const float sc = aval * __builtin_amdgcn_rcpf(denom);
    float4 o0, o1;
    o0.x = acc2[0][r]*sc; o0.y = acc2[1][r]*sc; o0.z = acc2[2][r]*sc; o0.w = acc2[3][r]*sc;
    o1.x = acc2[4][r]*sc; o1.y = acc2[5][r]*sc; o1.z = acc2[6][r]*sc; o1.w = acc2[7][r]*sc;
    size_t P = (size_t)blockIdx.x*16 + pos;
    float4* op = reinterpret_cast<float4*>(out + (P*64 + (size_t)oc)*8);
    op[0] = o0; op[1] = o1;
  }
}

extern "C" void kernel_launch(void* const* d_in, const int* in_sizes, int n_in,
                              void* d_out, int out_size, void* d_ws, size_t ws_size,
                              hipStream_t stream)
{
  const float* x  = (const float*)d_in[0];
  const float* W1 = (const float*)d_in[1];
  const float* b1 = (const float*)d_in[2];
  const float* W2 = (const float*)d_in[3];
  const float* b2 = (const float*)d_in[4];
  const float* a  = (const float*)d_in[5];
  float* out = (float*)d_out;

  u16* w1p = (u16*)d_ws;          // 64 KB
  u16* w2p = w1p + 32768;         // 64 KB

  gp_prepack<<<256, 256, 0, stream>>>(W1, W2, w1p, w2p);
  gp_fused<<<2048, 256, 0, stream>>>(x, w1p, b1, w2p, b2, a, out);
}